// Round 5
// baseline (485.096 us; speedup 1.0000x reference)
//
#include <hip/hip_runtime.h>
#include <cstdint>
#include <cstddef>

#define THRESH_F 0.5f
#define VAR0_F 0.1f
#define VAR1_F 0.2f
#define NEG_POS_K 3
#define MAXOBJ 64
#define ROWS_PER_BLK 128

// ---------------- init: zero the per-truth packed argmax slots ----------------
__global__ void init_kernel(unsigned long long* __restrict__ bp_packed, int nbp) {
    int i = blockIdx.x * blockDim.x + threadIdx.x;
    if (i < nbp) bp_packed[i] = 0ull;
}

// ---------------- kernel 1: matching. ballot-based per-truth wave argmax ----------------
__global__ __launch_bounds__(256)
void match_kernel(const float* __restrict__ priors,
                  const float* __restrict__ targets,
                  float* __restrict__ bto,
                  unsigned char* __restrict__ bti,
                  unsigned long long* __restrict__ bp_packed,
                  int P, int NOBJ) {
    int b = blockIdx.y;
    int tid = threadIdx.x;
    int lane = tid & 63;
    int p = blockIdx.x * blockDim.x + tid;
    bool valid = (p < P);
    __shared__ float tx1[MAXOBJ], ty1[MAXOBJ], tx2[MAXOBJ], ty2[MAXOBJ], ta[MAXOBJ];
    __shared__ unsigned long long smax[MAXOBJ];
    if (tid < (unsigned)NOBJ) {
        const float* t = targets + ((size_t)b * NOBJ + tid) * 5;
        float x1 = t[0], y1 = t[1], x2 = t[2], y2 = t[3];
        tx1[tid] = x1; ty1[tid] = y1;
        tx2[tid] = x2; ty2[tid] = y2;
        ta[tid] = (x2 - x1) * (y2 - y1);
        smax[tid] = 0ull;
    }
    __syncthreads();

    int pc = valid ? p : 0;
    const float4 prv = *(const float4*)(priors + (size_t)pc * 4);
    float cx = prv.x, cy = prv.y, w = prv.z, h = prv.w;
    float px1 = cx - w * 0.5f, py1 = cy - h * 0.5f;
    float px2 = cx + w * 0.5f, py2 = cy + h * 0.5f;
    float pa = (px2 - px1) * (py2 - py1);
    float best = -1.0f; int bidx = 0;

    for (int t = 0; t < NOBJ; ++t) {
        float lx = fmaxf(tx1[t], px1), ly = fmaxf(ty1[t], py1);
        float rx = fminf(tx2[t], px2), ry = fminf(ty2[t], py2);
        float iw = fmaxf(rx - lx, 0.0f), ih = fmaxf(ry - ly, 0.0f);
        float inter = iw * ih;
        float iou = inter / ((ta[t] + pa) - inter + 1e-10f);
        float iouv = valid ? iou : -1.0f;
        if (iouv > best) { best = iouv; bidx = t; }   // strict > : first-index tie like jnp.argmax
        // wave max of iou (f32, cheap), then ballot to find lowest-lane holder (= smallest p)
        float wm = iouv;
        #pragma unroll
        for (int o = 32; o > 0; o >>= 1) wm = fmaxf(wm, __shfl_xor(wm, o, 64));
        unsigned long long eq = __ballot(iouv == wm);
        int src = (int)__ffsll(eq) - 1;
        if (lane == src && valid) {
            unsigned long long pk = ((unsigned long long)__float_as_uint(iouv) << 32)
                                  | (unsigned long long)(0xFFFFFFFFu - (unsigned)p);
            if (pk > smax[t]) atomicMax(&smax[t], pk);   // ≤4 contenders/block, monotone-filtered
        }
    }
    if (valid) {
        bto[(size_t)b * P + p] = best;
        bti[(size_t)b * P + p] = (unsigned char)bidx;
    }
    __syncthreads();
    if (tid < (unsigned)NOBJ) {
        unsigned long long v = smax[tid];
        unsigned long long* dst = &bp_packed[(size_t)b * NOBJ + tid];
        if (v > *dst) atomicMax(dst, v);   // monotone, stale-read skip safe
    }
}

// ---------------- kernel 2: force-assign best prior per truth ----------------
__global__ void force_kernel(const unsigned long long* __restrict__ bp_packed,
                             float* __restrict__ bto, unsigned char* __restrict__ bti,
                             int P, int NOBJ, int B) {
    int b = blockIdx.x * blockDim.x + threadIdx.x;
    if (b >= B) return;
    for (int j = 0; j < NOBJ; ++j) {
        unsigned long long pk = bp_packed[(size_t)b * NOBJ + j];
        unsigned p = 0xFFFFFFFFu - (unsigned)(pk & 0xFFFFFFFFull);
        bto[(size_t)b * P + p] = 2.0f;
        bti[(size_t)b * P + p] = (unsigned char)j;
    }
}

// ---------------- kernel 3: LDS-staged row-per-thread logsumexp/ce/smooth-L1 ----------------
// Block = 128 threads stages 128 contiguous rows (41472 B) via float4, then each
// thread reduces its own row from LDS. No shuffles in the row reduction.
__global__ __launch_bounds__(128)
void ce_kernel(const float* __restrict__ loc,
               const float* __restrict__ conf,
               const float* __restrict__ priors,
               const float* __restrict__ targets,
               const float* __restrict__ bto,
               const unsigned char* __restrict__ bti,
               float* __restrict__ ce_mine,
               float* __restrict__ part_np,
               float* __restrict__ part_ce,
               float* __restrict__ part_ll,
               int P, int C, int NOBJ, int NBX) {
    __shared__ float srow[ROWS_PER_BLK * 81];   // 41472 B
    int b = blockIdx.y;
    int blk = blockIdx.x;
    int tid = threadIdx.x;
    int lane = tid & 63;
    int wid = tid >> 6;

    int rowsInBlk = P - blk * ROWS_PER_BLK;
    if (rowsInBlk > ROWS_PER_BLK) rowsInBlk = ROWS_PER_BLK;

    // ---- stage: contiguous float4 stream (16B-aligned: (b*P + blk*128)*81 % 4 == 0) ----
    size_t baseFloat = ((size_t)b * P + (size_t)blk * ROWS_PER_BLK) * 81;
    int totalF = rowsInBlk * 81;
    int nf4 = totalF >> 2;
    const float4* g4 = (const float4*)(conf + baseFloat);
    float4* s4 = (float4*)srow;
    for (int i = tid; i < nf4; i += ROWS_PER_BLK) s4[i] = g4[i];
    for (int i = (nf4 << 2) + tid; i < totalF; i += ROWS_PER_BLK) srow[i] = conf[baseFloat + i];
    __syncthreads();

    // ---- per-thread row reduction from LDS ----
    float cnt = 0.0f, ces = 0.0f, lls = 0.0f;
    int p = blk * ROWS_PER_BLK + tid;
    if (tid < rowsInBlk) {
        const float* lr = srow + tid * 81;
        float ma = lr[0], mb = lr[1], mc = lr[2], md = lr[3];
        #pragma unroll
        for (int j = 4; j < 80; j += 4) {
            ma = fmaxf(ma, lr[j]);     mb = fmaxf(mb, lr[j + 1]);
            mc = fmaxf(mc, lr[j + 2]); md = fmaxf(md, lr[j + 3]);
        }
        float m = fmaxf(fmaxf(ma, mb), fmaxf(mc, md));
        m = fmaxf(m, lr[80]);
        float sa = 0.0f, sb = 0.0f, sc = 0.0f, sd2 = 0.0f;
        #pragma unroll
        for (int j = 0; j < 80; j += 4) {
            sa += __expf(lr[j] - m);     sb += __expf(lr[j + 1] - m);
            sc += __expf(lr[j + 2] - m); sd2 += __expf(lr[j + 3] - m);
        }
        float s = ((sa + sb) + (sc + sd2)) + __expf(lr[80] - m);

        float lse = m + __logf(s);
        size_t row = (size_t)b * P + p;
        float ov = bto[row];
        int ti = bti[row];
        const float* tb = targets + ((size_t)b * NOBJ + ti) * 5;
        int cls = 0;
        if (ov >= THRESH_F) cls = (int)(tb[4] + 1.0f);
        float ce = lse - lr[cls];
        bool pos = cls > 0;
        ce_mine[row] = pos ? 0.0f : fmaxf(ce, 0.0f);   // clamp: keep radix keys sign-bit-free
        if (pos) {
            cnt = 1.0f;
            ces = ce;
            const float4 prv = *(const float4*)(priors + (size_t)p * 4);
            float pcx = prv.x, pcy = prv.y, pw = prv.z, ph = prv.w;
            float m0 = tb[0], m1 = tb[1], m2 = tb[2], m3 = tb[3];
            float g0 = ((m0 + m2) * 0.5f - pcx) / (VAR0_F * pw);
            float g1 = ((m1 + m3) * 0.5f - pcy) / (VAR0_F * ph);
            float g2 = __logf((m2 - m0) / pw + 1e-10f) / VAR1_F;
            float g3 = __logf((m3 - m1) / ph + 1e-10f) / VAR1_F;
            float g[4] = {g0, g1, g2, g3};
            const float4 lv = *(const float4*)(loc + row * 4);
            float l[4] = {lv.x, lv.y, lv.z, lv.w};
            float acc = 0.0f;
            #pragma unroll
            for (int d = 0; d < 4; ++d) {
                float diff = fabsf(l[d] - g[d]);
                acc += (diff < 1.0f) ? 0.5f * diff * diff : diff - 0.5f;
            }
            lls = acc;
        }
    }

    // ---- block reduce (2 waves) ----
    #pragma unroll
    for (int o = 32; o > 0; o >>= 1) {
        cnt += __shfl_xor(cnt, o, 64);
        ces += __shfl_xor(ces, o, 64);
        lls += __shfl_xor(lls, o, 64);
    }
    __syncthreads();               // all LDS row reads done before reuse
    float* red = srow;
    if (lane == 0) { red[wid * 3 + 0] = cnt; red[wid * 3 + 1] = ces; red[wid * 3 + 2] = lls; }
    __syncthreads();
    if (tid == 0) {
        size_t idx = (size_t)b * NBX + blk;
        part_np[idx] = red[0] + red[3];
        part_ce[idx] = red[1] + red[4];
        part_ll[idx] = red[2] + red[5];
    }
}

// ---------------- block reduction helper ----------------
__device__ inline double blockReduceD(double v, double* sd) {
    __syncthreads();
    #pragma unroll
    for (int o = 32; o > 0; o >>= 1) v += __shfl_xor(v, o, 64);
    int wid = threadIdx.x >> 6, lane = threadIdx.x & 63;
    if (lane == 0) sd[wid] = v;
    __syncthreads();
    if (threadIdx.x == 0) {
        double t = 0.0; int nw = blockDim.x >> 6;
        for (int i = 0; i < nw; ++i) t += sd[i];
        sd[0] = t;
    }
    __syncthreads();
    return sd[0];
}

// ---------------- kernel 4: per-batch partial-reduce + radix-select kth largest ----------------
// Histogram updates are wave-aggregated (ballot/leader/popcount) to kill the
// same-address LDS-atomic storm from clustered ce values.
__global__ __launch_bounds__(1024)
void select_kernel(const float* __restrict__ ce_mine,
                   const float* __restrict__ part_np,
                   const float* __restrict__ part_ce,
                   const float* __restrict__ part_ll,
                   double* __restrict__ np_b,
                   double* __restrict__ lc_b,
                   double* __restrict__ ll_b,
                   int P, int NBX) {
    int b = blockIdx.x;
    int tid = threadIdx.x;
    int lane = tid & 63;
    __shared__ unsigned int hist[256];
    __shared__ unsigned int s_prefix;
    __shared__ int s_krem;
    __shared__ double sd[16];

    // 1) reduce per-block partials for this batch
    double np_f = 0.0, ce_f = 0.0, ll_f = 0.0;
    for (int i = tid; i < NBX; i += blockDim.x) {
        size_t ix = (size_t)b * NBX + i;
        np_f += (double)part_np[ix];
        ce_f += (double)part_ce[ix];
        ll_f += (double)part_ll[ix];
    }
    double np_d = blockReduceD(np_f, sd);
    double ce_sum = blockReduceD(ce_f, sd);
    double ll_sum = blockReduceD(ll_f, sd);

    int np = (int)(np_d + 0.5);
    long long k = (long long)NEG_POS_K * np;
    if (k > P - 1) k = P - 1;

    if (k <= 0) {
        if (tid == 0) { np_b[b] = (double)np; lc_b[b] = ce_sum; ll_b[b] = ll_sum; }
        return;
    }

    // 2) radix-select kth largest (non-negative floats -> bits order-monotone)
    const float* vals = ce_mine + (size_t)b * P;
    unsigned prefix = 0;
    int krem = (int)k;
    for (int pass = 0; pass < 4; ++pass) {
        int shift = 24 - 8 * pass;
        unsigned mask_hi = (pass == 0) ? 0u : (0xFFFFFFFFu << (shift + 8));
        if (tid < 256) hist[tid] = 0;
        __syncthreads();
        for (int i0 = 0; i0 < P; i0 += 1024) {       // uniform trip count
            int i = i0 + tid;
            bool pred = (i < P);
            unsigned key = pred ? __float_as_uint(vals[i]) : 0u;
            pred = pred && ((key & mask_hi) == prefix);
            unsigned d = (key >> shift) & 255u;
            unsigned long long act = __ballot(pred);
            while (act) {
                int leader = (int)__ffsll(act) - 1;
                unsigned dl = (unsigned)__shfl((int)d, leader, 64);
                unsigned long long same = __ballot(pred && (d == dl));
                if (lane == leader) atomicAdd(&hist[dl], (unsigned)__popcll(same));
                act &= ~same;
            }
        }
        __syncthreads();
        if (tid == 0) {
            int kr = krem;
            int d = 255;
            for (;;) {
                int c = (int)hist[d];
                if (c >= kr || d == 0) break;
                kr -= c;
                --d;
            }
            s_prefix = prefix | ((unsigned)d << shift);
            s_krem = kr;
        }
        __syncthreads();
        prefix = s_prefix;
        krem = s_krem;
        __syncthreads();
    }

    // 3) sum of selected: strictly-above-threshold + krem * threshold (exact under ties)
    unsigned tbits = prefix;
    double s0 = 0.0, s1 = 0.0, s2 = 0.0, s3 = 0.0;
    int i = tid;
    for (; i + 3072 < P; i += 4096) {
        float v0 = vals[i], v1 = vals[i + 1024], v2 = vals[i + 2048], v3 = vals[i + 3072];
        if (__float_as_uint(v0) > tbits) s0 += (double)v0;
        if (__float_as_uint(v1) > tbits) s1 += (double)v1;
        if (__float_as_uint(v2) > tbits) s2 += (double)v2;
        if (__float_as_uint(v3) > tbits) s3 += (double)v3;
    }
    for (; i < P; i += 1024) {
        float v = vals[i];
        if (__float_as_uint(v) > tbits) s0 += (double)v;
    }
    double selsum = blockReduceD((s0 + s1) + (s2 + s3), sd);
    if (tid == 0) {
        np_b[b] = (double)np;
        lc_b[b] = ce_sum + selsum + (double)krem * (double)__uint_as_float(tbits);
        ll_b[b] = ll_sum;
    }
}

// ---------------- kernel 5: finalize (one wave) ----------------
__global__ void finalize_kernel(const double* __restrict__ np_b,
                                const double* __restrict__ lc_b,
                                const double* __restrict__ ll_b,
                                float* __restrict__ out, int B) {
    int t = threadIdx.x;
    double np = 0.0, lc = 0.0, ll = 0.0;
    for (int b = t; b < B; b += 64) { np += np_b[b]; lc += lc_b[b]; ll += ll_b[b]; }
    #pragma unroll
    for (int o = 32; o > 0; o >>= 1) {
        np += __shfl_xor(np, o, 64);
        lc += __shfl_xor(lc, o, 64);
        ll += __shfl_xor(ll, o, 64);
    }
    if (t == 0) {
        double N = np > 0.0 ? np : 1.0;
        out[0] = (float)(ll / N);
        out[1] = (float)(lc / N);
    }
}

extern "C" void kernel_launch(void* const* d_in, const int* in_sizes, int n_in,
                              void* d_out, int out_size, void* d_ws, size_t ws_size,
                              hipStream_t stream) {
    const float* loc     = (const float*)d_in[0];
    const float* conf    = (const float*)d_in[1];
    const float* priors  = (const float*)d_in[2];
    const float* targets = (const float*)d_in[3];

    int P = in_sizes[2] / 4;
    long long nloc = in_sizes[0];
    int B = (int)(nloc / ((long long)P * 4));
    int C = (int)((long long)in_sizes[1] / ((long long)B * P));
    int NOBJ = in_sizes[3] / (B * 5);
    int NBX = (P + ROWS_PER_BLK - 1) / ROWS_PER_BLK;

    size_t BP = (size_t)B * P;
    auto align256 = [](size_t x) { return (x + 255) & ~(size_t)255; };
    size_t off = 0;
    float* bto = (float*)((char*)d_ws + off);                 off = align256(off + BP * 4);
    unsigned char* bti = (unsigned char*)((char*)d_ws + off); off = align256(off + BP);
    float* ce_mine = (float*)((char*)d_ws + off);             off = align256(off + BP * 4);
    unsigned long long* bp_packed = (unsigned long long*)((char*)d_ws + off); off = align256(off + (size_t)B * NOBJ * 8);
    float* part_np = (float*)((char*)d_ws + off);             off = align256(off + (size_t)B * NBX * 4);
    float* part_ce = (float*)((char*)d_ws + off);             off = align256(off + (size_t)B * NBX * 4);
    float* part_ll = (float*)((char*)d_ws + off);             off = align256(off + (size_t)B * NBX * 4);
    double* np_b = (double*)((char*)d_ws + off);              off = align256(off + (size_t)B * 8);
    double* lc_b = (double*)((char*)d_ws + off);              off = align256(off + (size_t)B * 8);
    double* ll_b = (double*)((char*)d_ws + off);              off = align256(off + (size_t)B * 8);

    float* out = (float*)d_out;

    int nbp = B * NOBJ;
    init_kernel<<<(nbp + 255) / 256, 256, 0, stream>>>(bp_packed, nbp);

    dim3 mgrid((P + 255) / 256, B);
    match_kernel<<<mgrid, 256, 0, stream>>>(priors, targets, bto, bti, bp_packed, P, NOBJ);

    force_kernel<<<(B + 63) / 64, 64, 0, stream>>>(bp_packed, bto, bti, P, NOBJ, B);

    dim3 cgrid(NBX, B);
    ce_kernel<<<cgrid, 128, 0, stream>>>(loc, conf, priors, targets, bto, bti,
                                         ce_mine, part_np, part_ce, part_ll, P, C, NOBJ, NBX);

    select_kernel<<<B, 1024, 0, stream>>>(ce_mine, part_np, part_ce, part_ll,
                                          np_b, lc_b, ll_b, P, NBX);

    finalize_kernel<<<1, 64, 0, stream>>>(np_b, lc_b, ll_b, out, B);
}

// Round 6
// 347.966 us; speedup vs baseline: 1.3941x; 1.3941x over previous
//
#include <hip/hip_runtime.h>
#include <cstdint>
#include <cstddef>

#define THRESH_F 0.5f
#define VAR0_F 0.1f
#define VAR1_F 0.2f
#define NEG_POS_K 3
#define MAXOBJ 64

// ---------------- init: zero the per-truth packed argmax slots ----------------
__global__ void init_kernel(unsigned long long* __restrict__ bp_packed, int nbp) {
    int i = blockIdx.x * blockDim.x + threadIdx.x;
    if (i < nbp) bp_packed[i] = 0ull;
}

// ---------------- kernel 1: matching (round-4 butterfly version, measured-good) ----------------
__global__ __launch_bounds__(256)
void match_kernel(const float* __restrict__ priors,
                  const float* __restrict__ targets,
                  float* __restrict__ bto,
                  unsigned char* __restrict__ bti,
                  unsigned long long* __restrict__ bp_packed,
                  int P, int NOBJ) {
    int b = blockIdx.y;
    int tid = threadIdx.x;
    int lane = tid & 63;
    int p = blockIdx.x * blockDim.x + tid;
    bool valid = (p < P);
    __shared__ float tx1[MAXOBJ], ty1[MAXOBJ], tx2[MAXOBJ], ty2[MAXOBJ], ta[MAXOBJ];
    __shared__ unsigned long long smax[MAXOBJ];
    if (tid < (unsigned)NOBJ) {
        const float* t = targets + ((size_t)b * NOBJ + tid) * 5;
        float x1 = t[0], y1 = t[1], x2 = t[2], y2 = t[3];
        tx1[tid] = x1; ty1[tid] = y1;
        tx2[tid] = x2; ty2[tid] = y2;
        ta[tid] = (x2 - x1) * (y2 - y1);
        smax[tid] = 0ull;
    }
    __syncthreads();

    int pc = valid ? p : (P - 1);
    const float4 prv = *(const float4*)(priors + (size_t)pc * 4);
    float cx = prv.x, cy = prv.y, w = prv.z, h = prv.w;
    float px1 = cx - w * 0.5f, py1 = cy - h * 0.5f;
    float px2 = cx + w * 0.5f, py2 = cy + h * 0.5f;
    float pa = (px2 - px1) * (py2 - py1);
    float best = -1.0f; int bidx = 0;

    for (int t = 0; t < NOBJ; ++t) {
        float lx = fmaxf(tx1[t], px1), ly = fmaxf(ty1[t], py1);
        float rx = fminf(tx2[t], px2), ry = fminf(ty2[t], py2);
        float iw = fmaxf(rx - lx, 0.0f), ih = fmaxf(ry - ly, 0.0f);
        float inter = iw * ih;
        float iou = inter / ((ta[t] + pa) - inter + 1e-10f);
        if (iou > best) { best = iou; bidx = t; }   // strict > : first-index tie like jnp.argmax
        unsigned long long pk = valid ?
            (((unsigned long long)__float_as_uint(iou) << 32) |
             (unsigned long long)(0xFFFFFFFFu - (unsigned)p)) : 0ull;  // inverted idx: max picks smallest p
        #pragma unroll
        for (int o = 32; o > 0; o >>= 1) {
            unsigned long long other = __shfl_xor(pk, o, 64);
            if (other > pk) pk = other;
        }
        if (lane == 0 && pk > smax[t]) atomicMax(&smax[t], pk);  // 4 contenders/block, filtered
    }
    if (valid) {
        bto[(size_t)b * P + p] = best;
        bti[(size_t)b * P + p] = (unsigned char)bidx;
    }
    __syncthreads();
    if (tid < (unsigned)NOBJ) {
        unsigned long long v = smax[tid];
        unsigned long long* dst = &bp_packed[(size_t)b * NOBJ + tid];
        if (v > *dst) atomicMax(dst, v);   // monotone, stale-read skip safe
    }
}

// ---------------- kernel 2: force-assign best prior per truth ----------------
__global__ void force_kernel(const unsigned long long* __restrict__ bp_packed,
                             float* __restrict__ bto, unsigned char* __restrict__ bti,
                             int P, int NOBJ, int B) {
    int b = blockIdx.x * blockDim.x + threadIdx.x;
    if (b >= B) return;
    for (int j = 0; j < NOBJ; ++j) {
        unsigned long long pk = bp_packed[(size_t)b * NOBJ + j];
        unsigned p = 0xFFFFFFFFu - (unsigned)(pk & 0xFFFFFFFFull);
        bto[(size_t)b * P + p] = 2.0f;
        bti[(size_t)b * P + p] = (unsigned char)j;
    }
}

// ---------------- kernel 3: 16 lanes/row, float4 loads, no LDS staging, no global atomics ----
// 4 rows per wave, 16 rows per 256-thread block. Full occupancy (32 waves/CU).
__global__ __launch_bounds__(256)
void ce_kernel(const float* __restrict__ loc,
               const float* __restrict__ conf,
               const float* __restrict__ priors,
               const float* __restrict__ targets,
               const float* __restrict__ bto,
               const unsigned char* __restrict__ bti,
               float* __restrict__ ce_mine,
               float* __restrict__ part_np,
               float* __restrict__ part_ce,
               float* __restrict__ part_ll,
               int P, int C, int NOBJ) {
    int lane = threadIdx.x & 63;
    int wid = threadIdx.x >> 6;
    int q = lane >> 4;           // quarter-wave id 0..3
    int lq = lane & 15;          // lane within quarter
    int p = blockIdx.x * 16 + wid * 4 + q;
    int b = blockIdx.y;
    bool active = (p < P);
    size_t row = (size_t)b * P + p;
    const float* base = conf + row * 81;   // C = 81

    float cnt = 0.0f, ces = 0.0f, lls = 0.0f;

    if (active) {
        // elems 4lq..4lq+3 (all lanes), 64+4lq..67+4lq (lq<4), elem 80 (lq==4).
        // dwordx4 at 4-B alignment is legal on gfx9-lineage globals; all reads in-row.
        const float4* b4 = (const float4*)base;
        float4 va = b4[lq];
        bool hasB = (lq < 4);
        bool has80 = (lq == 4);
        float4 vb = hasB ? b4[16 + lq] : va;
        float s80 = has80 ? base[80] : -INFINITY;

        float m = fmaxf(fmaxf(va.x, va.y), fmaxf(va.z, va.w));
        if (hasB) m = fmaxf(m, fmaxf(fmaxf(vb.x, vb.y), fmaxf(vb.z, vb.w)));
        if (has80) m = fmaxf(m, s80);
        #pragma unroll
        for (int o = 8; o > 0; o >>= 1) m = fmaxf(m, __shfl_xor(m, o, 64));

        float s = __expf(va.x - m) + __expf(va.y - m) + __expf(va.z - m) + __expf(va.w - m);
        if (hasB) s += __expf(vb.x - m) + __expf(vb.y - m) + __expf(vb.z - m) + __expf(vb.w - m);
        if (has80) s += __expf(s80 - m);
        #pragma unroll
        for (int o = 8; o > 0; o >>= 1) s += __shfl_xor(s, o, 64);

        if (lq == 0) {
            float lse = m + __logf(s);
            float ov = bto[row];
            int ti = bti[row];
            const float* tb = targets + ((size_t)b * NOBJ + ti) * 5;
            int cls = 0;
            if (ov >= THRESH_F) cls = (int)(tb[4] + 1.0f);
            float ce = lse - base[cls];
            bool pos = cls > 0;
            ce_mine[row] = pos ? 0.0f : fmaxf(ce, 0.0f);  // clamp: radix keys sign-bit-free
            if (pos) {
                cnt = 1.0f;
                ces = ce;
                const float4 prv = *(const float4*)(priors + (size_t)p * 4);
                float pcx = prv.x, pcy = prv.y, pw = prv.z, ph = prv.w;
                float m0 = tb[0], m1 = tb[1], m2 = tb[2], m3 = tb[3];
                float g0 = ((m0 + m2) * 0.5f - pcx) / (VAR0_F * pw);
                float g1 = ((m1 + m3) * 0.5f - pcy) / (VAR0_F * ph);
                float g2 = __logf((m2 - m0) / pw + 1e-10f) / VAR1_F;
                float g3 = __logf((m3 - m1) / ph + 1e-10f) / VAR1_F;
                float g[4] = {g0, g1, g2, g3};
                const float4 lv = *(const float4*)(loc + row * 4);
                float l[4] = {lv.x, lv.y, lv.z, lv.w};
                float acc = 0.0f;
                #pragma unroll
                for (int d = 0; d < 4; ++d) {
                    float diff = fabsf(l[d] - g[d]);
                    acc += (diff < 1.0f) ? 0.5f * diff * diff : diff - 0.5f;
                }
                lls = acc;
            }
        }
    }

    // reduce the 4 quarter-leader lanes (0,16,32,48) of each wave, then across 4 waves
    cnt += __shfl_xor(cnt, 16, 64); cnt += __shfl_xor(cnt, 32, 64);
    ces += __shfl_xor(ces, 16, 64); ces += __shfl_xor(ces, 32, 64);
    lls += __shfl_xor(lls, 16, 64); lls += __shfl_xor(lls, 32, 64);

    __shared__ float s_np[4], s_ce[4], s_ll[4];
    if (lane == 0) { s_np[wid] = cnt; s_ce[wid] = ces; s_ll[wid] = lls; }
    __syncthreads();
    if (threadIdx.x == 0) {
        size_t idx = (size_t)b * gridDim.x + blockIdx.x;
        part_np[idx] = s_np[0] + s_np[1] + s_np[2] + s_np[3];
        part_ce[idx] = s_ce[0] + s_ce[1] + s_ce[2] + s_ce[3];
        part_ll[idx] = s_ll[0] + s_ll[1] + s_ll[2] + s_ll[3];
    }
}

// ---------------- block reduction helper ----------------
__device__ inline double blockReduceD(double v, double* sd) {
    __syncthreads();
    #pragma unroll
    for (int o = 32; o > 0; o >>= 1) v += __shfl_xor(v, o, 64);
    int wid = threadIdx.x >> 6, lane = threadIdx.x & 63;
    if (lane == 0) sd[wid] = v;
    __syncthreads();
    if (threadIdx.x == 0) {
        double t = 0.0; int nw = blockDim.x >> 6;
        for (int i = 0; i < nw; ++i) t += sd[i];
        sd[0] = t;
    }
    __syncthreads();
    return sd[0];
}

// ---------------- kernel 4: per-batch partial-reduce + radix-select kth largest ----------------
// Single-leader wave aggregation: collapses the dominant clustered bucket into one
// LDS atomic per wave; minority buckets fall back to plain per-lane atomics.
__global__ __launch_bounds__(1024)
void select_kernel(const float* __restrict__ ce_mine,
                   const float* __restrict__ part_np,
                   const float* __restrict__ part_ce,
                   const float* __restrict__ part_ll,
                   double* __restrict__ np_b,
                   double* __restrict__ lc_b,
                   double* __restrict__ ll_b,
                   int P, int NBX) {
    int b = blockIdx.x;
    int tid = threadIdx.x;
    int lane = tid & 63;
    __shared__ unsigned int hist[256];
    __shared__ unsigned int s_prefix;
    __shared__ int s_krem;
    __shared__ double sd[16];

    // 1) reduce per-block partials for this batch
    double np_f = 0.0, ce_f = 0.0, ll_f = 0.0;
    for (int i = tid; i < NBX; i += blockDim.x) {
        size_t ix = (size_t)b * NBX + i;
        np_f += (double)part_np[ix];
        ce_f += (double)part_ce[ix];
        ll_f += (double)part_ll[ix];
    }
    double np_d = blockReduceD(np_f, sd);
    double ce_sum = blockReduceD(ce_f, sd);
    double ll_sum = blockReduceD(ll_f, sd);

    int np = (int)(np_d + 0.5);
    long long k = (long long)NEG_POS_K * np;
    if (k > P - 1) k = P - 1;

    if (k <= 0) {
        if (tid == 0) { np_b[b] = (double)np; lc_b[b] = ce_sum; ll_b[b] = ll_sum; }
        return;
    }

    // 2) radix-select kth largest (non-negative floats -> bits order-monotone)
    const float* vals = ce_mine + (size_t)b * P;
    unsigned prefix = 0;
    int krem = (int)k;
    for (int pass = 0; pass < 4; ++pass) {
        int shift = 24 - 8 * pass;
        unsigned mask_hi = (pass == 0) ? 0u : (0xFFFFFFFFu << (shift + 8));
        if (tid < 256) hist[tid] = 0;
        __syncthreads();
        for (int i0 = 0; i0 < P; i0 += 1024) {       // uniform trip count
            int i = i0 + tid;
            bool pred = (i < P);
            unsigned key = pred ? __float_as_uint(vals[i]) : 0u;
            pred = pred && ((key & mask_hi) == prefix);
            unsigned d = (key >> shift) & 255u;
            unsigned long long act = __ballot(pred);
            if (act) {
                int leader = (int)__ffsll(act) - 1;
                unsigned dl = (unsigned)__shfl((int)d, leader, 64);
                unsigned long long same = __ballot(pred && (d == dl));
                if (lane == leader) atomicAdd(&hist[dl], (unsigned)__popcll(same));
                if (pred && d != dl) atomicAdd(&hist[d], 1u);
            }
        }
        __syncthreads();
        if (tid == 0) {
            int kr = krem;
            int d = 255;
            for (;;) {
                int c = (int)hist[d];
                if (c >= kr || d == 0) break;
                kr -= c;
                --d;
            }
            s_prefix = prefix | ((unsigned)d << shift);
            s_krem = kr;
        }
        __syncthreads();
        prefix = s_prefix;
        krem = s_krem;
        __syncthreads();
    }

    // 3) sum of selected: strictly-above-threshold + krem * threshold (exact under ties)
    unsigned tbits = prefix;
    double s0 = 0.0, s1 = 0.0, s2 = 0.0, s3 = 0.0;
    int i = tid;
    for (; i + 3072 < P; i += 4096) {
        float v0 = vals[i], v1 = vals[i + 1024], v2 = vals[i + 2048], v3 = vals[i + 3072];
        if (__float_as_uint(v0) > tbits) s0 += (double)v0;
        if (__float_as_uint(v1) > tbits) s1 += (double)v1;
        if (__float_as_uint(v2) > tbits) s2 += (double)v2;
        if (__float_as_uint(v3) > tbits) s3 += (double)v3;
    }
    for (; i < P; i += 1024) {
        float v = vals[i];
        if (__float_as_uint(v) > tbits) s0 += (double)v;
    }
    double selsum = blockReduceD((s0 + s1) + (s2 + s3), sd);
    if (tid == 0) {
        np_b[b] = (double)np;
        lc_b[b] = ce_sum + selsum + (double)krem * (double)__uint_as_float(tbits);
        ll_b[b] = ll_sum;
    }
}

// ---------------- kernel 5: finalize (one wave) ----------------
__global__ void finalize_kernel(const double* __restrict__ np_b,
                                const double* __restrict__ lc_b,
                                const double* __restrict__ ll_b,
                                float* __restrict__ out, int B) {
    int t = threadIdx.x;
    double np = 0.0, lc = 0.0, ll = 0.0;
    for (int b = t; b < B; b += 64) { np += np_b[b]; lc += lc_b[b]; ll += ll_b[b]; }
    #pragma unroll
    for (int o = 32; o > 0; o >>= 1) {
        np += __shfl_xor(np, o, 64);
        lc += __shfl_xor(lc, o, 64);
        ll += __shfl_xor(ll, o, 64);
    }
    if (t == 0) {
        double N = np > 0.0 ? np : 1.0;
        out[0] = (float)(ll / N);
        out[1] = (float)(lc / N);
    }
}

extern "C" void kernel_launch(void* const* d_in, const int* in_sizes, int n_in,
                              void* d_out, int out_size, void* d_ws, size_t ws_size,
                              hipStream_t stream) {
    const float* loc     = (const float*)d_in[0];
    const float* conf    = (const float*)d_in[1];
    const float* priors  = (const float*)d_in[2];
    const float* targets = (const float*)d_in[3];

    int P = in_sizes[2] / 4;
    long long nloc = in_sizes[0];
    int B = (int)(nloc / ((long long)P * 4));
    int C = (int)((long long)in_sizes[1] / ((long long)B * P));
    int NOBJ = in_sizes[3] / (B * 5);
    int NBX = (P + 15) / 16;

    size_t BP = (size_t)B * P;
    auto align256 = [](size_t x) { return (x + 255) & ~(size_t)255; };
    size_t off = 0;
    float* bto = (float*)((char*)d_ws + off);                 off = align256(off + BP * 4);
    unsigned char* bti = (unsigned char*)((char*)d_ws + off); off = align256(off + BP);
    float* ce_mine = (float*)((char*)d_ws + off);             off = align256(off + BP * 4);
    unsigned long long* bp_packed = (unsigned long long*)((char*)d_ws + off); off = align256(off + (size_t)B * NOBJ * 8);
    float* part_np = (float*)((char*)d_ws + off);             off = align256(off + (size_t)B * NBX * 4);
    float* part_ce = (float*)((char*)d_ws + off);             off = align256(off + (size_t)B * NBX * 4);
    float* part_ll = (float*)((char*)d_ws + off);             off = align256(off + (size_t)B * NBX * 4);
    double* np_b = (double*)((char*)d_ws + off);              off = align256(off + (size_t)B * 8);
    double* lc_b = (double*)((char*)d_ws + off);              off = align256(off + (size_t)B * 8);
    double* ll_b = (double*)((char*)d_ws + off);              off = align256(off + (size_t)B * 8);

    float* out = (float*)d_out;

    int nbp = B * NOBJ;
    init_kernel<<<(nbp + 255) / 256, 256, 0, stream>>>(bp_packed, nbp);

    dim3 mgrid((P + 255) / 256, B);
    match_kernel<<<mgrid, 256, 0, stream>>>(priors, targets, bto, bti, bp_packed, P, NOBJ);

    force_kernel<<<(B + 63) / 64, 64, 0, stream>>>(bp_packed, bto, bti, P, NOBJ, B);

    dim3 cgrid(NBX, B);
    ce_kernel<<<cgrid, 256, 0, stream>>>(loc, conf, priors, targets, bto, bti,
                                         ce_mine, part_np, part_ce, part_ll, P, C, NOBJ);

    select_kernel<<<B, 1024, 0, stream>>>(ce_mine, part_np, part_ce, part_ll,
                                          np_b, lc_b, ll_b, P, NBX);

    finalize_kernel<<<1, 64, 0, stream>>>(np_b, lc_b, ll_b, out, B);
}